// Round 1
// 102.252 us; speedup vs baseline: 1.0218x; 1.0218x over previous
//
#include <hip/hip_runtime.h>

typedef __attribute__((ext_vector_type(8))) short short8;
typedef __attribute__((ext_vector_type(2))) float float2_t;
typedef __attribute__((ext_vector_type(4))) float float4_t;
typedef __attribute__((ext_vector_type(16))) float float16_t;

#define NB 32
#define NL 256
#define ND 128
#define OUT_PLANE (NB * ND * NL)   // elements per stacked output plane
#define XS 136                     // LDS row stride (bf16): conflict-free b128
#define BUFSZ (18 * XS)
#define FR_WORD 49152              // word-frag offset in ws (bf16 units)
#define CHRB 98304                 // bf16 chr_table offset in ws (bf16 units)

__device__ inline unsigned short f2bf(float f) {
    union { float f; unsigned int i; } c;
    c.f = f;
    unsigned int r = c.i + 0x7FFFu + ((c.i >> 16) & 1u);  // RN-even
    return (unsigned short)(r >> 16);
}

// ---------------------------------------------------------------------------
// ws prep, vectorized: 8 consecutive elements per thread (one short8 store),
// grid = 56 x 256 (exact). Within an 8-octet only j varies; t is constant
// (kk0 is a multiple of 8, so the octet never crosses the d=128 boundary).
//  [0..49151]      char B-frags for 32x32x16: frag[s][nt][lane][j]
//  [49152..98303]  word B-frags for 16x16x32 (R6 layout)
//  [98304..114687] chr_table converted to bf16 (row 0 stays all-zero)
// ---------------------------------------------------------------------------
__global__ void make_frags(const float* __restrict__ Wc,
                           const float* __restrict__ Ww,
                           const float* __restrict__ chrT,
                           unsigned short* __restrict__ out) {
    const int i0 = (blockIdx.x * 256 + threadIdx.x) * 8;  // 0..114680, step 8
    unsigned short v[8];
    if (i0 < FR_WORD) {                                  // char 32x32 frags
        int lane = (i0 >> 3) & 63;
        int nt   = (i0 >> 9) & 3;
        int s    = i0 >> 11;                             // 0..23
        int dout = nt * 32 + (lane & 31);
        int kk0  = s * 16 + ((lane >> 5) & 1) * 8;       // multiple of 8
        int t    = kk0 >> 7;
        int d0   = kk0 & 127;
        const float* src = Wc + (dout * 128 + d0) * 3 + t;
#pragma unroll
        for (int j = 0; j < 8; ++j) v[j] = f2bf(src[j * 3]);
    } else if (i0 < CHRB) {                              // word 16x16 frags
        int ii   = i0 - FR_WORD;
        int lane = (ii >> 3) & 63;
        int nt   = (ii >> 9) & 7;
        int s    = ii >> 12;
        int dout = nt * 16 + (lane & 15);
        int t    = s >> 2;
        int k0   = (s & 3) * 32 + ((lane >> 4) & 3) * 8; // multiple of 8
        const float* src = Ww + (dout * 128 + k0) * 3 + t;
#pragma unroll
        for (int j = 0; j < 8; ++j) v[j] = f2bf(src[j * 3]);
    } else {                                             // bf16 chr_table
        const float* src = chrT + (i0 - CHRB);
        float4_t f0 = *(const float4_t*)(src);
        float4_t f1 = *(const float4_t*)(src + 4);
        v[0] = f2bf(f0.x); v[1] = f2bf(f0.y); v[2] = f2bf(f0.z); v[3] = f2bf(f0.w);
        v[4] = f2bf(f1.x); v[5] = f2bf(f1.y); v[6] = f2bf(f1.z); v[7] = f2bf(f1.w);
    }
    *(short8*)&out[i0] = *(const short8*)v;
}

// ---------------------------------------------------------------------------
// Merged conv kernel, grid = 1536. CHAR FIRST (longest blocks dispatch
// earliest): blocks 0..1023 char path (8 words as 4 dual-word 32x32x16
// pairs); blocks 1024..1535 word path (16x16x32, 16 l per block).
// 4 rotating LDS buffers, one barrier per pair; staging for words j+2/j+3
// issued under the two MFMA half-blocks. 128 thr = 2 waves.
// Char epilogue: per-pair results land in LDS OT[8][128]; one coalesced
// 32B-per-dout store phase at the end (was: 8B stores at 1KB stride = 4-16x
// write amplification on the char output plane).
// ---------------------------------------------------------------------------
__global__ __launch_bounds__(128, 2) void conv_kernel(
    const int* __restrict__ wv, const int* __restrict__ wic,
    const float* __restrict__ wordT,
    const unsigned short* __restrict__ ws,
    const float* __restrict__ biasC, const float* __restrict__ biasW,
    float* __restrict__ out) {
    __shared__ unsigned short X[4][BUFSZ];
    __shared__ float OT[8][128];       // char-path output tile [l][dout]
    const int tid  = threadIdx.x;
    const int wave = tid >> 6, lane = tid & 63;
    const int bid = blockIdx.x;

    if (bid < 1024) {
        // ------------------------- char path -------------------------------
        const unsigned short* chrB = ws + CHRB;
        const int w0 = bid * 8;                // 8 consecutive words, same b
        const int b = w0 >> 8, l0 = w0 & 255;
        const int n32 = lane & 31;             // output col within ntile
        const int h   = (lane >> 5) & 1;       // k-half
        const int r15 = lane & 15;             // c-position within word
        const int wsel = (lane >> 4) & 1;      // 0: word j, 1: word j+1

        short8 bfrag[24][2];
#pragma unroll
        for (int s = 0; s < 24; ++s)
#pragma unroll
            for (int p = 0; p < 2; ++p)
                bfrag[s][p] = *(const short8*)(
                    ws + (((s * 4 + wave * 2 + p) * 64 + lane) << 3));
        float bc[2];
#pragma unroll
        for (int p = 0; p < 2; ++p) bc[p] = biasC[wave * 64 + p * 32 + n32];

        // zero pad rows (c=-1 and c=16) in all 4 buffers; never overwritten
        for (int p = tid; p < XS; p += 128)
#pragma unroll
            for (int q = 0; q < 4; ++q) { X[q][p] = 0; X[q][17 * XS + p] = 0; }

        // staging map: 256 jobs/word = 16 rows x 16 chunks of 8 shorts (16B);
        // thread stages rows ra, ra+8 at chunk sub
        const int ra = tid >> 4, sub = tid & 15;

        // prologue: stage words 0,1 into X[0],X[1]
#pragma unroll
        for (int q = 0; q < 2; ++q) {
            int j0 = wic[(w0 + q) * 16 + ra];
            int j1 = wic[(w0 + q) * 16 + ra + 8];
            short8 g0 = *(const short8*)(chrB + j0 * 128 + sub * 8);
            short8 g1 = *(const short8*)(chrB + j1 * 128 + sub * 8);
            *(short8*)&X[q][(ra + 1) * XS + sub * 8] = g0;
            *(short8*)&X[q][(ra + 9) * XS + sub * 8] = g1;
        }
        int iA0 = wic[(w0 + 2) * 16 + ra];       // word j+2 idx
        int iA1 = wic[(w0 + 2) * 16 + ra + 8];
        int iC0 = wic[(w0 + 3) * 16 + ra];       // word j+3 idx
        int iC1 = wic[(w0 + 3) * 16 + ra + 8];
        __syncthreads();

#pragma unroll
        for (int j = 0; j < 8; j += 2) {         // 4 dual-word pairs
            const unsigned short* abuf = X[(j + wsel) & 3];

            short8 g0, g1;
            if (j < 6) {   // staging loads for word j+2 under MFMA half 1
                g0 = *(const short8*)(chrB + iA0 * 128 + sub * 8);
                g1 = *(const short8*)(chrB + iA1 * 128 + sub * 8);
            }

            float16_t acc[2];
#pragma unroll
            for (int p = 0; p < 2; ++p)
#pragma unroll
                for (int e = 0; e < 16; ++e) acc[p][e] = 0.f;

#pragma unroll
            for (int s = 0; s < 12; ++s) {       // MFMA half 1
                short8 a = *(const short8*)&abuf[(r15 + (s >> 3)) * XS +
                                                 (s & 7) * 16 + h * 8];
#pragma unroll
                for (int p = 0; p < 2; ++p)
                    acc[p] = __builtin_amdgcn_mfma_f32_32x32x16_bf16(
                        a, bfrag[s][p], acc[p], 0, 0, 0);
            }

            short8 h0, h1;
            if (j < 6) {   // write word j+2; load word j+3 under half 2
                *(short8*)&X[(j + 2) & 3][(ra + 1) * XS + sub * 8] = g0;
                *(short8*)&X[(j + 2) & 3][(ra + 9) * XS + sub * 8] = g1;
                h0 = *(const short8*)(chrB + iC0 * 128 + sub * 8);
                h1 = *(const short8*)(chrB + iC1 * 128 + sub * 8);
                if (j < 4) {   // prefetch idx for words j+4, j+5
                    iA0 = wic[(w0 + j + 4) * 16 + ra];
                    iA1 = wic[(w0 + j + 4) * 16 + ra + 8];
                    iC0 = wic[(w0 + j + 5) * 16 + ra];
                    iC1 = wic[(w0 + j + 5) * 16 + ra + 8];
                }
            }

#pragma unroll
            for (int s = 12; s < 24; ++s) {      // MFMA half 2
                short8 a = *(const short8*)&abuf[(r15 + (s >> 3)) * XS +
                                                 (s & 7) * 16 + h * 8];
#pragma unroll
                for (int p = 0; p < 2; ++p)
                    acc[p] = __builtin_amdgcn_mfma_f32_32x32x16_bf16(
                        a, bfrag[s][p], acc[p], 0, 0, 0);
            }

            if (j < 6) {
                *(short8*)&X[(j + 3) & 3][(ra + 1) * XS + sub * 8] = h0;
                *(short8*)&X[(j + 3) & 3][(ra + 9) * XS + sub * 8] = h1;
            }

            // epilogue: rows = c (word0: regs 0..7, word1: regs 8..15);
            // col = lane&31; xor-32 merges the two k-half row groups.
            // Park results in OT[l][dout] (conflict-free: 32 consecutive
            // dout per write); global store deferred to coalesced phase.
#pragma unroll
            for (int p = 0; p < 2; ++p) {
                float v0 = acc[p][0], v1 = acc[p][8];
#pragma unroll
                for (int e = 1; e < 8; ++e) {
                    v0 = fmaxf(v0, acc[p][e]);
                    v1 = fmaxf(v1, acc[p][e + 8]);
                }
                v0 = fmaxf(v0, __shfl_xor(v0, 32, 64));
                v1 = fmaxf(v1, __shfl_xor(v1, 32, 64));
                if (lane < 32) {
                    int dout = wave * 64 + p * 32 + n32;
                    OT[j][dout]     = v0 + bc[p];
                    OT[j + 1][dout] = v1 + bc[p];
                }
            }
            __syncthreads();  // protects next pair's buffer overwrites + OT
        }

        // coalesced store phase: thread tid owns dout = tid; 32B contiguous
        // per dout (2 x float4), lanes stride NL*4 = 1KB. LDS reads OT[e][tid]
        // are 2-way bank-aliased (free).
        {
            float r[8];
#pragma unroll
            for (int e = 0; e < 8; ++e) r[e] = OT[e][tid];
            float* obase = out + OUT_PLANE + b * (ND * NL) + tid * NL + l0;
            float4_t s0 = {r[0], r[1], r[2], r[3]};
            float4_t s1 = {r[4], r[5], r[6], r[7]};
            *(float4_t*)&obase[0] = s0;
            *(float4_t*)&obase[4] = s1;
        }
    } else {
        // ------------------------- word path (16x16x32) --------------------
        const int wb = bid - 1024;
        const int m = lane & 15, quad = lane >> 4;
        const int b = wb >> 4, l0 = (wb & 15) << 4;
        short8 bfrag[12][4];
#pragma unroll
        for (int s = 0; s < 12; ++s)
#pragma unroll
            for (int p = 0; p < 4; ++p)
                bfrag[s][p] = *(const short8*)(
                    ws + FR_WORD + (((s * 8 + wave * 4 + p) * 64 + lane) << 3));
        float bb[4];
#pragma unroll
        for (int p = 0; p < 4; ++p) bb[p] = biasW[wave * 64 + p * 16 + m];

#pragma unroll
        for (int i0 = 0; i0 < 2; ++i0) {   // 18 rows x 8 segs = 144 jobs
            int i = tid + i0 * 128;
            if (i < 144) {
                int rr = i >> 3, sg = i & 7;
                int l = l0 + rr - 1;
                int idx = (l >= 0 && l < NL) ? wv[b * NL + l] : 0;  // row0=0s
                const float4_t* src =
                    (const float4_t*)(wordT + idx * 128 + sg * 16);
                float4_t f0 = src[0], f1 = src[1], f2 = src[2], f3 = src[3];
                unsigned short t16[16];
                t16[0]=f2bf(f0.x); t16[1]=f2bf(f0.y); t16[2]=f2bf(f0.z); t16[3]=f2bf(f0.w);
                t16[4]=f2bf(f1.x); t16[5]=f2bf(f1.y); t16[6]=f2bf(f1.z); t16[7]=f2bf(f1.w);
                t16[8]=f2bf(f2.x); t16[9]=f2bf(f2.y); t16[10]=f2bf(f2.z); t16[11]=f2bf(f2.w);
                t16[12]=f2bf(f3.x); t16[13]=f2bf(f3.y); t16[14]=f2bf(f3.z); t16[15]=f2bf(f3.w);
                *(short8*)&X[0][rr * XS + sg * 16]     = *(const short8*)&t16[0];
                *(short8*)&X[0][rr * XS + sg * 16 + 8] = *(const short8*)&t16[8];
            }
        }
        __syncthreads();

        float4_t acc[4];
#pragma unroll
        for (int p = 0; p < 4; ++p) acc[p] = (float4_t){0.f, 0.f, 0.f, 0.f};
#pragma unroll
        for (int s = 0; s < 12; ++s) {
            short8 a = *(const short8*)&X[0][(m + (s >> 2)) * XS +
                                            (s & 3) * 32 + quad * 8];
#pragma unroll
            for (int p = 0; p < 4; ++p)
                acc[p] = __builtin_amdgcn_mfma_f32_16x16x32_bf16(
                    a, bfrag[s][p], acc[p], 0, 0, 0);
        }

        // D[row = l_local = quad*4+reg][col = dout_local = m]; 4 l's per lane
        // (4-lane m-groups already cover full 64B segments — coalesced)
        float* obase = out + b * (ND * NL) + l0 + quad * 4;
#pragma unroll
        for (int p = 0; p < 4; ++p) {
            int dout = wave * 64 + p * 16 + m;
            float4_t pk;
            pk.x = acc[p].x + bb[p];
            pk.y = acc[p].y + bb[p];
            pk.z = acc[p].z + bb[p];
            pk.w = acc[p].w + bb[p];
            *(float4_t*)&obase[dout * NL] = pk;
        }
    }
}

extern "C" void kernel_launch(void* const* d_in, const int* in_sizes, int n_in,
                              void* d_out, int out_size, void* d_ws,
                              size_t ws_size, hipStream_t stream) {
    const int* word_vector   = (const int*)d_in[0];
    const int* words_in_char = (const int*)d_in[1];
    const float* word_table  = (const float*)d_in[2];
    const float* chr_table   = (const float*)d_in[3];
    const float* conv_chr_w  = (const float*)d_in[4];
    const float* conv_chr_b  = (const float*)d_in[5];
    const float* conv_word_w = (const float*)d_in[6];
    const float* conv_word_b = (const float*)d_in[7];
    float* out            = (float*)d_out;
    unsigned short* wsp   = (unsigned short*)d_ws;  // frags + bf16 chr_table

    make_frags<<<56, 256, 0, stream>>>(conv_chr_w, conv_word_w, chr_table, wsp);
    conv_kernel<<<1536, 128, 0, stream>>>(word_vector, words_in_char,
                                          word_table, wsp,
                                          conv_chr_b, conv_word_b, out);
}